// Round 4
// baseline (2072.002 us; speedup 1.0000x reference)
//
#include <hip/hip_runtime.h>

#define NCAT 32
#define NTOK 512
#define HID  512
#define EMB  1024
#define DSTATE 192
#define CHUNK 32
#define MAXW 48

// ws layout:
//   [0,128)        int cnt[32]
//   [128,136)      int nW[1]        (chunks of 32 tokens; sum ceil(n/32) <= 47)
//   [256,448)      int work[48]     entries: cat | (chunk<<8)
//   [1024,66560)   int toklist[32][512]
//   [66560,+4MiB)  float H[512 tok][4 mod][512]

__global__ __launch_bounds__(512) void bucket_kernel(
    const int* __restrict__ ids, int* __restrict__ cnt, int* __restrict__ nW,
    int* __restrict__ work, int* __restrict__ toklist)
{
    __shared__ int scnt[NCAT];
    const int tid = threadIdx.x;
    if (tid < NCAT) scnt[tid] = 0;
    __syncthreads();
    const int c = ids[tid];                       // 512 threads == 512 tokens
    const int pos = atomicAdd(&scnt[c], 1);       // LDS atomic: cheap
    toklist[c * NTOK + pos] = tid;
    __syncthreads();
    if (tid == 0) {
        int n1 = 0;
        for (int cc = 0; cc < NCAT; ++cc) {
            const int n = scnt[cc];
            cnt[cc] = n;
            for (int ch = 0; ch * CHUNK < n; ++ch) work[n1++] = cc | (ch << 8);
        }
        nW[0] = n1;
    }
}

// grid (48 slots, 4 mod, 2 colhalf), 128 threads. 32 tokens/block zero-padded.
// sX is transposed [k][t]: per k, token operands are broadcast ds_read_b128.
// Thread owns 2 hid cols (z*256 + 2*tid); FMA-bound (~3.4us/block serial).
__global__ __launch_bounds__(128, 2) void layer1_kernel(
    const float* __restrict__ state,
    const int* __restrict__ cnt, const int* __restrict__ toklist,
    const int* __restrict__ nW, const int* __restrict__ work,
    const float* __restrict__ W1_0, const float* __restrict__ W1_1,
    const float* __restrict__ W1_2, const float* __restrict__ W1_3,
    const float* __restrict__ b1_0, const float* __restrict__ b1_1,
    const float* __restrict__ b1_2, const float* __restrict__ b1_3,
    float* __restrict__ H)
{
    const int slot = blockIdx.x, mod = blockIdx.y, z = blockIdx.z;
    if (slot >= nW[0]) return;
    const int ent = work[slot];
    const int cat = ent & 255, chunk = ent >> 8;
    const int nC = cnt[cat];
    const int start = chunk * CHUNK;
    int nThis = nC - start;
    if (nThis > CHUNK) nThis = CHUNK;
    const int tid = threadIdx.x;

    const int L   = (mod < 2) ? 64 : 32;
    const int off = (mod == 0) ? 0 : (mod == 1) ? 64 : (mod == 2) ? 128 : 160;

    __shared__ float sX[64 * 32];                 // [k][t], 8 KiB max
    __shared__ int sTok[32];
    if (tid < 32) sTok[tid] = (tid < nThis) ? toklist[cat * NTOK + start + tid] : 0;
    __syncthreads();

    {   // transposed stage: tt = tid&31 owns token tt; kg = tid>>5 owns L/4 k-rows
        const int tt = tid & 31, kg = tid >> 5;
        const int rpk = L >> 2;                   // 16 or 8 rows per kg
        const float* src = state + (size_t)sTok[tt] * DSTATE + off + kg * rpk;
        const int nf4 = rpk >> 2;                 // 4 or 2 float4 per thread
        for (int j = 0; j < nf4; ++j) {
            float4 v = make_float4(0.f, 0.f, 0.f, 0.f);
            if (tt < nThis) v = ((const float4*)src)[j];
            const int k0 = kg * rpk + j * 4;
            sX[(k0 + 0) * 32 + tt] = v.x;
            sX[(k0 + 1) * 32 + tt] = v.y;
            sX[(k0 + 2) * 32 + tt] = v.z;
            sX[(k0 + 3) * 32 + tt] = v.w;
        }
    }
    __syncthreads();

    const float* W1 = (mod == 0) ? W1_0 : (mod == 1) ? W1_1 : (mod == 2) ? W1_2 : W1_3;
    const float* b1 = (mod == 0) ? b1_0 : (mod == 1) ? b1_1 : (mod == 2) ? b1_2 : b1_3;
    const int col = z * 256 + 2 * tid;
    const float* Wc = W1 + (size_t)cat * L * HID + col;

    float2 acc[32];
#pragma unroll
    for (int t = 0; t < 32; ++t) acc[t] = make_float2(0.f, 0.f);

#pragma unroll 8
    for (int k = 0; k < L; ++k) {
        const float2 w = *(const float2*)(Wc + (size_t)k * HID);
        const float4* hp = (const float4*)(sX + k * 32);
#pragma unroll
        for (int q = 0; q < 8; ++q) {
            const float4 hq = hp[q];
            acc[4*q+0].x += hq.x * w.x; acc[4*q+0].y += hq.x * w.y;
            acc[4*q+1].x += hq.y * w.x; acc[4*q+1].y += hq.y * w.y;
            acc[4*q+2].x += hq.z * w.x; acc[4*q+2].y += hq.z * w.y;
            acc[4*q+3].x += hq.w * w.x; acc[4*q+3].y += hq.w * w.y;
        }
    }

    const float2 b = *(const float2*)(b1 + cat * HID + col);
#pragma unroll
    for (int t = 0; t < 32; ++t) {
        if (t >= nThis) break;
        float2 h;
        h.x = acc[t].x + b.x; h.x = h.x > 0.f ? h.x : 0.f;
        h.y = acc[t].y + b.y; h.y = h.y > 0.f ? h.y : 0.f;
        *(float2*)(H + (size_t)(sTok[t] * 4 + mod) * HID + col) = h;
    }
}

// grid (48 slots, 4 mod, 2 colhalf), 256 threads. 32 tokens/block zero-padded.
// W2 panel streamed through a 3-deep pipeline: regs hold tile t+2 (4 named
// float4), LDS double-buffer holds tiles t, t+1 (8 rows x 512 cols each).
// Loads issue one full compute phase before their ds_write -> HBM latency
// structurally hidden (no reliance on compiler load reordering).
// sH transposed [k][t] -> token operands are broadcast ds_read_b128.
__global__ __launch_bounds__(256, 1) void layer2_kernel(
    const int* __restrict__ cnt, const int* __restrict__ toklist,
    const int* __restrict__ nW, const int* __restrict__ work,
    const float* __restrict__ H,
    const float* __restrict__ W2_0, const float* __restrict__ W2_1,
    const float* __restrict__ W2_2, const float* __restrict__ W2_3,
    const float* __restrict__ b2_0, const float* __restrict__ b2_1,
    const float* __restrict__ b2_2, const float* __restrict__ b2_3,
    const float* __restrict__ te_0, const float* __restrict__ te_1,
    const float* __restrict__ te_2, const float* __restrict__ te_3,
    float* __restrict__ out)
{
    const int slot = blockIdx.x, mod = blockIdx.y, z = blockIdx.z;
    if (slot >= nW[0]) return;
    const int ent = work[slot];
    const int cat = ent & 255, chunk = ent >> 8;
    const int nC = cnt[cat];
    const int start = chunk * CHUNK;
    int nThis = nC - start;
    if (nThis > CHUNK) nThis = CHUNK;
    const int tid = threadIdx.x;
    const int zbase = z * 512;

    __shared__ float sH[512 * 32];                // 64 KiB, [k][t]
    __shared__ float wbuf[2][8 * 512];            // 2 x 16 KiB W tiles
    __shared__ int sTok[32];

    const float* W2 = (mod == 0) ? W2_0 : (mod == 1) ? W2_1 : (mod == 2) ? W2_2 : W2_3;
    const float* Wc = W2 + (size_t)cat * (HID * EMB) + zbase;

    // ISSUE(tile 0) immediately -- loads fly while we stage sH.
    const int r0 = tid >> 7;                      // 0 or 1
    const int cc4 = (tid & 127) * 4;              // col within 512-half
    float4 rw0, rw1, rw2, rw3;
    {
        const float* g = Wc;
        rw0 = *(const float4*)(g + (size_t)(r0 + 0) * EMB + cc4);
        rw1 = *(const float4*)(g + (size_t)(r0 + 2) * EMB + cc4);
        rw2 = *(const float4*)(g + (size_t)(r0 + 4) * EMB + cc4);
        rw3 = *(const float4*)(g + (size_t)(r0 + 6) * EMB + cc4);
    }

    if (tid < 32) sTok[tid] = (tid < nThis) ? toklist[cat * NTOK + start + tid] : 0;
    __syncthreads();

    {   // stage sH transposed: tt owns token tt, kg = tid>>5 owns 64 k-rows
        const int tt = tid & 31, kg = tid >> 5;
        const float* src = H + (size_t)(sTok[tt] * 4 + mod) * HID + kg * 64;
#pragma unroll
        for (int j = 0; j < 16; ++j) {
            float4 v = make_float4(0.f, 0.f, 0.f, 0.f);
            if (tt < nThis) v = ((const float4*)src)[j];
            const int k0 = kg * 64 + j * 4;
            sH[(k0 + 0) * 32 + tt] = v.x;
            sH[(k0 + 1) * 32 + tt] = v.y;
            sH[(k0 + 2) * 32 + tt] = v.z;
            sH[(k0 + 3) * 32 + tt] = v.w;
        }
    }

    {   // WRITE(tile 0) -> wbuf[0]   (compiler inserts vmcnt for rw deps)
        float4* wb = (float4*)wbuf[0];
        wb[0 * 256 + tid] = rw0; wb[1 * 256 + tid] = rw1;
        wb[2 * 256 + tid] = rw2; wb[3 * 256 + tid] = rw3;
    }
    {   // ISSUE(tile 1)
        const float* g = Wc + (size_t)8 * EMB;
        rw0 = *(const float4*)(g + (size_t)(r0 + 0) * EMB + cc4);
        rw1 = *(const float4*)(g + (size_t)(r0 + 2) * EMB + cc4);
        rw2 = *(const float4*)(g + (size_t)(r0 + 4) * EMB + cc4);
        rw3 = *(const float4*)(g + (size_t)(r0 + 6) * EMB + cc4);
    }
    __syncthreads();

    float2 acc[32];
#pragma unroll
    for (int t = 0; t < 32; ++t) acc[t] = make_float2(0.f, 0.f);

#pragma unroll 1
    for (int t = 0; t < 64; ++t) {                // 64 tiles of 8 k-rows
        const int cur = t & 1;
        const float* wb = wbuf[cur];
        const int kbase = t * 8;
#pragma unroll
        for (int r = 0; r < 8; ++r) {
            const float2 w = *(const float2*)(wb + r * 512 + 2 * tid);
            const float4* hp = (const float4*)(sH + (kbase + r) * 32);
#pragma unroll
            for (int q = 0; q < 8; ++q) {
                const float4 hq = hp[q];
                acc[4*q+0].x += hq.x * w.x; acc[4*q+0].y += hq.x * w.y;
                acc[4*q+1].x += hq.y * w.x; acc[4*q+1].y += hq.y * w.y;
                acc[4*q+2].x += hq.z * w.x; acc[4*q+2].y += hq.z * w.y;
                acc[4*q+3].x += hq.w * w.x; acc[4*q+3].y += hq.w * w.y;
            }
        }
        __syncthreads();                          // everyone done reading wbuf[cur]
        if (t + 1 < 64) {
            float4* wb2 = (float4*)wbuf[cur ^ 1]; // tile t+1 (loads had ~1 tile to land)
            wb2[0 * 256 + tid] = rw0; wb2[1 * 256 + tid] = rw1;
            wb2[2 * 256 + tid] = rw2; wb2[3 * 256 + tid] = rw3;
            if (t + 2 < 64) {                     // ISSUE(tile t+2)
                const float* g = Wc + (size_t)((t + 2) * 8) * EMB;
                rw0 = *(const float4*)(g + (size_t)(r0 + 0) * EMB + cc4);
                rw1 = *(const float4*)(g + (size_t)(r0 + 2) * EMB + cc4);
                rw2 = *(const float4*)(g + (size_t)(r0 + 4) * EMB + cc4);
                rw3 = *(const float4*)(g + (size_t)(r0 + 6) * EMB + cc4);
            }
        }
        __syncthreads();                          // wbuf[cur^1] visible for next iter
    }

    const float* b2 = (mod == 0) ? b2_0 : (mod == 1) ? b2_1 : (mod == 2) ? b2_2 : b2_3;
    const float* te = (mod == 0) ? te_0 : (mod == 1) ? te_1 : (mod == 2) ? te_2 : te_3;
    const int col = zbase + 2 * tid;
    const float2 bb = *(const float2*)(b2 + cat * EMB + col);
    const float2 tt = *(const float2*)(te + col);
    const float2 b4 = make_float2(bb.x + tt.x, bb.y + tt.y);
#pragma unroll
    for (int t = 0; t < 32; ++t) {
        if (t >= nThis) break;
        *(float2*)(out + (size_t)(sTok[t] * 4 + mod) * EMB + col) =
            make_float2(acc[t].x + b4.x, acc[t].y + b4.y);
    }
}

extern "C" void kernel_launch(void* const* d_in, const int* in_sizes, int n_in,
                              void* d_out, int out_size, void* d_ws, size_t ws_size,
                              hipStream_t stream) {
    const float* state = (const float*)d_in[0];
    const int*   ids   = (const int*)d_in[1];
    const float *W1[4], *b1[4], *W2[4], *b2[4], *te[4];
    for (int m = 0; m < 4; ++m) {
        W1[m] = (const float*)d_in[2 + 5 * m + 0];
        b1[m] = (const float*)d_in[2 + 5 * m + 1];
        W2[m] = (const float*)d_in[2 + 5 * m + 2];
        b2[m] = (const float*)d_in[2 + 5 * m + 3];
        te[m] = (const float*)d_in[2 + 5 * m + 4];
    }
    char* ws = (char*)d_ws;
    int*   cnt     = (int*)ws;
    int*   nW      = (int*)(ws + 128);
    int*   work    = (int*)(ws + 256);
    int*   toklist = (int*)(ws + 1024);
    float* H       = (float*)(ws + 66560);
    float* out     = (float*)d_out;

    bucket_kernel<<<1, 512, 0, stream>>>(ids, cnt, nW, work, toklist);
    layer1_kernel<<<dim3(MAXW, 4, 2), 128, 0, stream>>>(
        state, cnt, toklist, nW, work,
        W1[0], W1[1], W1[2], W1[3],
        b1[0], b1[1], b1[2], b1[3], H);
    layer2_kernel<<<dim3(MAXW, 4, 2), 256, 0, stream>>>(
        cnt, toklist, nW, work, H,
        W2[0], W2[1], W2[2], W2[3],
        b2[0], b2[1], b2[2], b2[3],
        te[0], te[1], te[2], te[3], out);
}

// Round 5
// 340.561 us; speedup vs baseline: 6.0841x; 6.0841x over previous
//
#include <hip/hip_runtime.h>

#define NCAT 32
#define NTOK 512
#define HID  512
#define EMB  1024
#define DSTATE 192
#define CHUNK 32
#define MAXW 48

// ws layout:
//   [0,128)        int cnt[32]
//   [128,136)      int nW[1]        (chunks of 32 tokens; sum ceil(n/32) <= 47)
//   [256,448)      int work[48]     entries: cat | (chunk<<8)
//   [1024,66560)   int toklist[32][512]
//   [66560,+4MiB)  float H[512 tok][4 mod][512]

__global__ __launch_bounds__(512) void bucket_kernel(
    const int* __restrict__ ids, int* __restrict__ cnt, int* __restrict__ nW,
    int* __restrict__ work, int* __restrict__ toklist)
{
    __shared__ int scnt[NCAT];
    const int tid = threadIdx.x;
    if (tid < NCAT) scnt[tid] = 0;
    __syncthreads();
    const int c = ids[tid];                       // 512 threads == 512 tokens
    const int pos = atomicAdd(&scnt[c], 1);       // LDS atomic: cheap
    toklist[c * NTOK + pos] = tid;
    __syncthreads();
    if (tid == 0) {
        int n1 = 0;
        for (int cc = 0; cc < NCAT; ++cc) {
            const int n = scnt[cc];
            cnt[cc] = n;
            for (int ch = 0; ch * CHUNK < n; ++ch) work[n1++] = cc | (ch << 8);
        }
        nW[0] = n1;
    }
}

// async global->LDS, 16 B per lane. LDS dest must be wave-uniform base
// (+ lane*16 added by HW); global src is per-lane.
__device__ __forceinline__ void async_copy16(void* lds_dst, const void* g_src) {
    __builtin_amdgcn_global_load_lds(
        (__attribute__((address_space(1))) void*)(g_src),
        (__attribute__((address_space(3))) void*)(lds_dst),
        16, 0, 0);
}

// grid (48 slots, 4 mod, 2 colhalf), 256 threads. 32 tokens/block zero-padded.
// sX transposed [k][t]. Thread = (tg=tid>>6: 8 tokens, cg=tid&63: 4 cols of
// the 256-col z-half). W read direct from global, unroll-4 ILP.
__global__ __launch_bounds__(256, 2) void layer1_kernel(
    const float* __restrict__ state,
    const int* __restrict__ cnt, const int* __restrict__ toklist,
    const int* __restrict__ nW, const int* __restrict__ work,
    const float* __restrict__ W1_0, const float* __restrict__ W1_1,
    const float* __restrict__ W1_2, const float* __restrict__ W1_3,
    const float* __restrict__ b1_0, const float* __restrict__ b1_1,
    const float* __restrict__ b1_2, const float* __restrict__ b1_3,
    float* __restrict__ H)
{
    const int slot = blockIdx.x, mod = blockIdx.y, z = blockIdx.z;
    if (slot >= nW[0]) return;
    const int ent = work[slot];
    const int cat = ent & 255, chunk = ent >> 8;
    const int nC = cnt[cat];
    const int start = chunk * CHUNK;
    int nThis = nC - start;
    if (nThis > CHUNK) nThis = CHUNK;
    const int tid = threadIdx.x;
    const int tg = tid >> 6;                       // wave id: 8-token group
    const int cg = tid & 63;                       // 4-col group

    const int L   = (mod < 2) ? 64 : 32;
    const int off = (mod == 0) ? 0 : (mod == 1) ? 64 : (mod == 2) ? 128 : 160;

    __shared__ float sX[64 * 32];                  // [k][t], 8 KiB
    __shared__ int sTok[CHUNK];
    if (tid < CHUNK) sTok[tid] = (tid < nThis) ? toklist[cat * NTOK + start + tid] : 0;
    __syncthreads();

    {   // transposed stage: tt owns token tt, kg = tid>>5 owns L/8 k-rows
        const int tt = tid & 31, kg = tid >> 5;
        const int rpk = L >> 3;                    // 8 or 4 rows per kg
        const float* src = state + (size_t)sTok[tt] * DSTATE + off + kg * rpk;
        const bool ok = tt < nThis;
        for (int j = 0; j < (rpk >> 2); ++j) {
            float4 v = make_float4(0.f, 0.f, 0.f, 0.f);
            if (ok) v = ((const float4*)src)[j];
            const int k0 = kg * rpk + (j << 2);
            sX[(k0 + 0) * 32 + tt] = v.x;
            sX[(k0 + 1) * 32 + tt] = v.y;
            sX[(k0 + 2) * 32 + tt] = v.z;
            sX[(k0 + 3) * 32 + tt] = v.w;
        }
    }
    __syncthreads();

    const float* W1 = (mod == 0) ? W1_0 : (mod == 1) ? W1_1 : (mod == 2) ? W1_2 : W1_3;
    const float* b1 = (mod == 0) ? b1_0 : (mod == 1) ? b1_1 : (mod == 2) ? b1_2 : b1_3;
    const int colA = z * 256 + (cg << 2);
    const float* Wc = W1 + (size_t)cat * L * HID + colA;
    const int hbase = tg << 3;
    const bool act = hbase < nThis;

    float4 acc[8];
#pragma unroll
    for (int i = 0; i < 8; ++i) acc[i] = make_float4(0.f, 0.f, 0.f, 0.f);

    if (act) {
#pragma unroll 4
        for (int k = 0; k < L; ++k) {
            const float4 w  = *(const float4*)(Wc + (size_t)k * HID);
            const float4 h0 = *(const float4*)(sX + k * 32 + hbase);
            const float4 h1 = *(const float4*)(sX + k * 32 + hbase + 4);
#define L1FMA(i, s) acc[i].x += (s)*w.x; acc[i].y += (s)*w.y; \
                    acc[i].z += (s)*w.z; acc[i].w += (s)*w.w;
            L1FMA(0, h0.x) L1FMA(1, h0.y) L1FMA(2, h0.z) L1FMA(3, h0.w)
            L1FMA(4, h1.x) L1FMA(5, h1.y) L1FMA(6, h1.z) L1FMA(7, h1.w)
#undef L1FMA
        }
    }

    const float4 b = *(const float4*)(b1 + cat * HID + colA);
#pragma unroll
    for (int i = 0; i < 8; ++i) {
        const int t = hbase + i;
        if (t >= nThis) break;
        float4 h;
        h.x = acc[i].x + b.x; h.x = h.x > 0.f ? h.x : 0.f;
        h.y = acc[i].y + b.y; h.y = h.y > 0.f ? h.y : 0.f;
        h.z = acc[i].z + b.z; h.z = h.z > 0.f ? h.z : 0.f;
        h.w = acc[i].w + b.w; h.w = h.w > 0.f ? h.w : 0.f;
        *(float4*)(H + (size_t)(sTok[t] * 4 + mod) * HID + colA) = h;
    }
}

// grid (48 slots, 4 mod, 2 colhalf), 256 threads. 32 tokens/block zero-padded.
// Weight-stationary: block streams its 1 MB W2 half-panel exactly once via
// global_load_lds double-buffer (64 tiles of 8 rows x 512 cols, 16 KiB each);
// stage of tile t+1 issues BEFORE compute of tile t; one barrier per tile
// (compiler drains vmcnt there). sH transposed [k][t]. Thread = 8 tok x 8 col
// (two lane-contiguous quads: cg*4 and 256+cg*4).
__global__ __launch_bounds__(256, 1) void layer2_kernel(
    const int* __restrict__ cnt, const int* __restrict__ toklist,
    const int* __restrict__ nW, const int* __restrict__ work,
    const float* __restrict__ H,
    const float* __restrict__ W2_0, const float* __restrict__ W2_1,
    const float* __restrict__ W2_2, const float* __restrict__ W2_3,
    const float* __restrict__ b2_0, const float* __restrict__ b2_1,
    const float* __restrict__ b2_2, const float* __restrict__ b2_3,
    const float* __restrict__ te_0, const float* __restrict__ te_1,
    const float* __restrict__ te_2, const float* __restrict__ te_3,
    float* __restrict__ out)
{
    const int slot = blockIdx.x, mod = blockIdx.y, z = blockIdx.z;
    if (slot >= nW[0]) return;
    const int ent = work[slot];
    const int cat = ent & 255, chunk = ent >> 8;
    const int nC = cnt[cat];
    const int start = chunk * CHUNK;
    int nThis = nC - start;
    if (nThis > CHUNK) nThis = CHUNK;
    const int tid = threadIdx.x;
    const int tg = tid >> 6;                       // wave id: 8-token group
    const int cg = tid & 63;                       // col group
    const int zbase = z * 512;

    __shared__ float sH[512 * 32];                 // 64 KiB, [k][t]
    __shared__ float wbuf[2][8 * 512];             // 2 x 16 KiB W tiles
    __shared__ int sTok[CHUNK];

    if (tid < CHUNK) sTok[tid] = (tid < nThis) ? toklist[cat * NTOK + start + tid] : 0;
    __syncthreads();

    const float* W2 = (mod == 0) ? W2_0 : (mod == 1) ? W2_1 : (mod == 2) ? W2_2 : W2_3;
    const float* Wc = W2 + (size_t)cat * (HID * EMB) + zbase;

    // Stage tile T (k-rows [T*8, T*8+8)) into wb. 4 sweeps of 4 KiB:
    // sweep s covers rows {2s, 2s+(tid>>7)}, thread's 16 B at col (tid&127)*4.
    // LDS dest is wave-uniform: wb + wave*256 floats + s*1024 floats.
#define STAGE_TILE(T, wb) do {                                                  \
        const float* gsrc_ = Wc + (size_t)((T) * 8 + (tid >> 7)) * EMB          \
                             + ((tid & 127) << 2);                              \
        float* ldst_ = (wb) + ((tid >> 6) << 8);                                \
        async_copy16(ldst_,        gsrc_);                                      \
        async_copy16(ldst_ + 1024, gsrc_ + 2 * EMB);                            \
        async_copy16(ldst_ + 2048, gsrc_ + 4 * EMB);                            \
        async_copy16(ldst_ + 3072, gsrc_ + 6 * EMB);                            \
    } while (0)

    STAGE_TILE(0, wbuf[0]);                        // tile-0 loads fly during sH stage

    {   // stage sH transposed: tt owns token tt, kg = tid>>5 owns 64 k-rows
        const int tt = tid & 31, kg = tid >> 5;
        const float* src = H + (size_t)(sTok[tt] * 4 + mod) * HID + (kg << 6);
        const bool ok = tt < nThis;
#pragma unroll
        for (int j = 0; j < 16; ++j) {
            float4 v = make_float4(0.f, 0.f, 0.f, 0.f);
            if (ok) v = ((const float4*)src)[j];
            const int k0 = (kg << 6) + (j << 2);
            sH[(k0 + 0) * 32 + tt] = v.x;
            sH[(k0 + 1) * 32 + tt] = v.y;
            sH[(k0 + 2) * 32 + tt] = v.z;
            sH[(k0 + 3) * 32 + tt] = v.w;
        }
    }
    __syncthreads();                               // sH + tile0 ready (vmcnt drained)

    const int hbase = tg << 3;
    const int wcol  = cg << 2;                     // quad A; quad B at +256
    const bool act  = hbase < nThis;

    float4 a0[8], a1[8];
#pragma unroll
    for (int i = 0; i < 8; ++i) {
        a0[i] = make_float4(0.f, 0.f, 0.f, 0.f);
        a1[i] = make_float4(0.f, 0.f, 0.f, 0.f);
    }

#pragma unroll 1
    for (int T = 0; T < 64; ++T) {
        if (T + 1 < 64) STAGE_TILE(T + 1, wbuf[(T + 1) & 1]);
        if (act) {
            const float* wb = wbuf[T & 1];
            const int kb = T << 3;
#pragma unroll
            for (int r = 0; r < 8; ++r) {
                const float4 h0 = *(const float4*)(sH + (kb + r) * 32 + hbase);
                const float4 h1 = *(const float4*)(sH + (kb + r) * 32 + hbase + 4);
                const float4 w0 = *(const float4*)(wb + r * 512 + wcol);
                const float4 w1 = *(const float4*)(wb + r * 512 + 256 + wcol);
#define FMA2(i, s) a0[i].x += (s)*w0.x; a0[i].y += (s)*w0.y;                    \
                   a0[i].z += (s)*w0.z; a0[i].w += (s)*w0.w;                    \
                   a1[i].x += (s)*w1.x; a1[i].y += (s)*w1.y;                    \
                   a1[i].z += (s)*w1.z; a1[i].w += (s)*w1.w;
                FMA2(0, h0.x) FMA2(1, h0.y) FMA2(2, h0.z) FMA2(3, h0.w)
                FMA2(4, h1.x) FMA2(5, h1.y) FMA2(6, h1.z) FMA2(7, h1.w)
#undef FMA2
            }
        }
        __syncthreads();                           // tile T+1 landed; wbuf[T&1] free
    }
#undef STAGE_TILE

    const float* b2 = (mod == 0) ? b2_0 : (mod == 1) ? b2_1 : (mod == 2) ? b2_2 : b2_3;
    const float* te = (mod == 0) ? te_0 : (mod == 1) ? te_1 : (mod == 2) ? te_2 : te_3;
    const int colA = zbase + wcol;
    const int colB = colA + 256;
    const float4 bA = *(const float4*)(b2 + cat * EMB + colA);
    const float4 bB = *(const float4*)(b2 + cat * EMB + colB);
    const float4 tA = *(const float4*)(te + colA);
    const float4 tB = *(const float4*)(te + colB);
#pragma unroll
    for (int i = 0; i < 8; ++i) {
        const int t = hbase + i;
        if (t >= nThis) break;
        float* op = out + (size_t)(sTok[t] * 4 + mod) * EMB;
        *(float4*)(op + colA) = make_float4(a0[i].x + bA.x + tA.x,
                                            a0[i].y + bA.y + tA.y,
                                            a0[i].z + bA.z + tA.z,
                                            a0[i].w + bA.w + tA.w);
        *(float4*)(op + colB) = make_float4(a1[i].x + bB.x + tB.x,
                                            a1[i].y + bB.y + tB.y,
                                            a1[i].z + bB.z + tB.z,
                                            a1[i].w + bB.w + tB.w);
    }
}

extern "C" void kernel_launch(void* const* d_in, const int* in_sizes, int n_in,
                              void* d_out, int out_size, void* d_ws, size_t ws_size,
                              hipStream_t stream) {
    const float* state = (const float*)d_in[0];
    const int*   ids   = (const int*)d_in[1];
    const float *W1[4], *b1[4], *W2[4], *b2[4], *te[4];
    for (int m = 0; m < 4; ++m) {
        W1[m] = (const float*)d_in[2 + 5 * m + 0];
        b1[m] = (const float*)d_in[2 + 5 * m + 1];
        W2[m] = (const float*)d_in[2 + 5 * m + 2];
        b2[m] = (const float*)d_in[2 + 5 * m + 3];
        te[m] = (const float*)d_in[2 + 5 * m + 4];
    }
    char* ws = (char*)d_ws;
    int*   cnt     = (int*)ws;
    int*   nW      = (int*)(ws + 128);
    int*   work    = (int*)(ws + 256);
    int*   toklist = (int*)(ws + 1024);
    float* H       = (float*)(ws + 66560);
    float* out     = (float*)d_out;

    bucket_kernel<<<1, 512, 0, stream>>>(ids, cnt, nW, work, toklist);
    layer1_kernel<<<dim3(MAXW, 4, 2), 256, 0, stream>>>(
        state, cnt, toklist, nW, work,
        W1[0], W1[1], W1[2], W1[3],
        b1[0], b1[1], b1[2], b1[3], H);
    layer2_kernel<<<dim3(MAXW, 4, 2), 256, 0, stream>>>(
        cnt, toklist, nW, work, H,
        W2[0], W2[1], W2[2], W2[3],
        b2[0], b2[1], b2[2], b2[3],
        te[0], te[1], te[2], te[3], out);
}

// Round 6
// 328.574 us; speedup vs baseline: 6.3060x; 1.0365x over previous
//
#include <hip/hip_runtime.h>

#define NCAT 32
#define NTOK 512
#define HID  512
#define EMB  1024
#define DSTATE 192
#define CHUNK 32
#define MAXW 48

// ws layout:
//   [0,128)        int cnt[32]
//   [128,136)      int nW[1]        (chunks of 32 tokens; sum ceil(n/32) <= 47)
//   [256,448)      int work[48]     entries: cat | (chunk<<8)
//   [1024,66560)   int toklist[32][512]
//   (no H buffer -- layer1 fused into layer2, H lives in LDS)

__global__ __launch_bounds__(512) void bucket_kernel(
    const int* __restrict__ ids, int* __restrict__ cnt, int* __restrict__ nW,
    int* __restrict__ work, int* __restrict__ toklist)
{
    __shared__ int scnt[NCAT];
    const int tid = threadIdx.x;
    if (tid < NCAT) scnt[tid] = 0;
    __syncthreads();
    const int c = ids[tid];                       // 512 threads == 512 tokens
    const int pos = atomicAdd(&scnt[c], 1);       // LDS atomic: cheap
    toklist[c * NTOK + pos] = tid;
    __syncthreads();
    if (tid == 0) {
        int n1 = 0;
        for (int cc = 0; cc < NCAT; ++cc) {
            const int n = scnt[cc];
            cnt[cc] = n;
            for (int ch = 0; ch * CHUNK < n; ++ch) work[n1++] = cc | (ch << 8);
        }
        nW[0] = n1;
    }
}

// async global->LDS, 16 B per lane. LDS dest wave-uniform base (+lane*16 by HW).
__device__ __forceinline__ void async_copy16(void* lds_dst, const void* g_src) {
    __builtin_amdgcn_global_load_lds(
        (__attribute__((address_space(1))) void*)(g_src),
        (__attribute__((address_space(3))) void*)(lds_dst),
        16, 0, 0);
}

// Fused layer1+layer2. grid (48 slots, 4 mod, 2 colhalf), 256 threads.
// Per block: stage X (32 tok x L) -> LDS transposed; layer1 in-register
// (thread owns 2 H cols); H -> LDS [k][token-quad XOR-swizzled]; then stream
// the 1 MB W2 half-panel via global_load_lds, TRIPLE-buffered and staged
// 2 tiles ahead with counted s_waitcnt vmcnt(4) + raw s_barrier per tile
// (T3/T4: loads stay in flight across barriers; never vmcnt(0) mid-loop).
__global__ __launch_bounds__(256, 1) void fused_kernel(
    const float* __restrict__ state,
    const int* __restrict__ cnt, const int* __restrict__ toklist,
    const int* __restrict__ nW, const int* __restrict__ work,
    const float* __restrict__ W1_0, const float* __restrict__ W1_1,
    const float* __restrict__ W1_2, const float* __restrict__ W1_3,
    const float* __restrict__ b1_0, const float* __restrict__ b1_1,
    const float* __restrict__ b1_2, const float* __restrict__ b1_3,
    const float* __restrict__ W2_0, const float* __restrict__ W2_1,
    const float* __restrict__ W2_2, const float* __restrict__ W2_3,
    const float* __restrict__ b2_0, const float* __restrict__ b2_1,
    const float* __restrict__ b2_2, const float* __restrict__ b2_3,
    const float* __restrict__ te_0, const float* __restrict__ te_1,
    const float* __restrict__ te_2, const float* __restrict__ te_3,
    float* __restrict__ out)
{
    const int slot = blockIdx.x, mod = blockIdx.y, z = blockIdx.z;
    if (slot >= nW[0]) return;
    const int ent = work[slot];
    const int cat = ent & 255, chunk = ent >> 8;
    const int nC = cnt[cat];
    const int start = chunk * CHUNK;
    int nThis = nC - start;
    if (nThis > CHUNK) nThis = CHUNK;
    const int tid = threadIdx.x;
    const int tg = tid >> 6;                       // wave id: 8-token group
    const int cg = tid & 63;                       // col group

    const int L   = (mod < 2) ? 64 : 32;
    const int off = (mod == 0) ? 0 : (mod == 1) ? 64 : (mod == 2) ? 128 : 160;

    __shared__ float sX[64 * 32];                  // [k][t], 8 KiB
    __shared__ float sH[512 * 32];                 // [k][token-quad swz], 64 KiB
    __shared__ float wbuf[3][8 * 512];             // 3 x 16 KiB W tiles
    __shared__ int sTok[CHUNK];

    if (tid < CHUNK) sTok[tid] = (tid < nThis) ? toklist[cat * NTOK + start + tid] : 0;
    __syncthreads();

    {   // stage sX transposed: tt owns token tt, kg = tid>>5 owns L/8 k-rows
        const int tt = tid & 31, kg = tid >> 5;
        const int rpk = L >> 3;                    // 8 or 4 rows per kg
        const float* src = state + (size_t)sTok[tt] * DSTATE + off + kg * rpk;
        const bool ok = tt < nThis;
        for (int j = 0; j < (rpk >> 2); ++j) {
            float4 v = make_float4(0.f, 0.f, 0.f, 0.f);
            if (ok) v = ((const float4*)src)[j];
            const int k0 = kg * rpk + (j << 2);
            sX[(k0 + 0) * 32 + tt] = v.x;
            sX[(k0 + 1) * 32 + tt] = v.y;
            sX[(k0 + 2) * 32 + tt] = v.z;
            sX[(k0 + 3) * 32 + tt] = v.w;
        }
    }
    __syncthreads();

    // ---- layer1: thread owns H cols {2tid, 2tid+1} across 32 tokens ----
    const float* W1 = (mod == 0) ? W1_0 : (mod == 1) ? W1_1 : (mod == 2) ? W1_2 : W1_3;
    const float* b1 = (mod == 0) ? b1_0 : (mod == 1) ? b1_1 : (mod == 2) ? b1_2 : b1_3;
    const float* W1c = W1 + (size_t)cat * L * HID + 2 * tid;

    float2 hacc[32];
#pragma unroll
    for (int t = 0; t < 32; ++t) hacc[t] = make_float2(0.f, 0.f);

#pragma unroll 4
    for (int k = 0; k < L; ++k) {
        const float2 w = *(const float2*)(W1c + (size_t)k * HID);
        const float4* xp = (const float4*)(sX + k * 32);
#pragma unroll
        for (int q = 0; q < 8; ++q) {
            const float4 x4 = xp[q];
            hacc[4*q+0].x += x4.x * w.x; hacc[4*q+0].y += x4.x * w.y;
            hacc[4*q+1].x += x4.y * w.x; hacc[4*q+1].y += x4.y * w.y;
            hacc[4*q+2].x += x4.z * w.x; hacc[4*q+2].y += x4.z * w.y;
            hacc[4*q+3].x += x4.w * w.x; hacc[4*q+3].y += x4.w * w.y;
        }
    }
    {   // bias + relu; write sH rows {2tid,2tid+1}; token-quad q at q^(tid&7)
        // (write: 64 lanes spread over all 8 quad-slots -> conflict-free;
        //  read side is wave-uniform broadcast -> swizzle-transparent)
        const float2 bb = *(const float2*)(b1 + cat * HID + 2 * tid);
        float4* s4 = (float4*)sH;
        const int key = tid & 7;
        const int r0 = 2 * tid, r1 = 2 * tid + 1;
#pragma unroll
        for (int q = 0; q < 8; ++q) {
            float4 v0, v1;
            v0.x = fmaxf(hacc[4*q+0].x + bb.x, 0.f);
            v0.y = fmaxf(hacc[4*q+1].x + bb.x, 0.f);
            v0.z = fmaxf(hacc[4*q+2].x + bb.x, 0.f);
            v0.w = fmaxf(hacc[4*q+3].x + bb.x, 0.f);
            v1.x = fmaxf(hacc[4*q+0].y + bb.y, 0.f);
            v1.y = fmaxf(hacc[4*q+1].y + bb.y, 0.f);
            v1.z = fmaxf(hacc[4*q+2].y + bb.y, 0.f);
            v1.w = fmaxf(hacc[4*q+3].y + bb.y, 0.f);
            s4[r0 * 8 + (q ^ key)] = v0;
            s4[r1 * 8 + (q ^ key)] = v1;
        }
    }

    // ---- layer2: stream W2 half-panel, 64 tiles of 8 rows x 512 cols ----
    const float* W2 = (mod == 0) ? W2_0 : (mod == 1) ? W2_1 : (mod == 2) ? W2_2 : W2_3;
    const float* Wc = W2 + (size_t)cat * (HID * EMB) + z * 512;

#define STAGE_TILE(T, wb) do {                                                  \
        const float* gsrc_ = Wc + (size_t)((T) * 8 + (tid >> 7)) * EMB          \
                             + ((tid & 127) << 2);                              \
        float* ldst_ = (wb) + ((tid >> 6) << 8);                                \
        async_copy16(ldst_,        gsrc_);                                      \
        async_copy16(ldst_ + 1024, gsrc_ + 2 * EMB);                            \
        async_copy16(ldst_ + 2048, gsrc_ + 4 * EMB);                            \
        async_copy16(ldst_ + 3072, gsrc_ + 6 * EMB);                            \
    } while (0)

    STAGE_TILE(0, wbuf[0]);
    STAGE_TILE(1, wbuf[1]);
    // tile0 landed (4 newest in flight = tile1), own sH ds_writes done; barrier
    asm volatile("s_waitcnt vmcnt(4) lgkmcnt(0)" ::: "memory");
    __builtin_amdgcn_s_barrier();
    asm volatile("" ::: "memory");
    __builtin_amdgcn_sched_barrier(0);

    const int hbase = tg << 3;                     // token base
    const int tq0   = tg << 1;                     // token-quad base
    const int wcol  = cg << 2;                     // quad A col; quad B at +256
    const bool act  = hbase < nThis;

    float4 a0[8], a1[8];
#pragma unroll
    for (int i = 0; i < 8; ++i) {
        a0[i] = make_float4(0.f, 0.f, 0.f, 0.f);
        a1[i] = make_float4(0.f, 0.f, 0.f, 0.f);
    }

    int bcur = 0;
#pragma unroll 1
    for (int T = 0; T < 64; ++T) {
        int b2i = bcur + 2; if (b2i >= 3) b2i -= 3;
        if (T + 2 < 64) STAGE_TILE(T + 2, wbuf[b2i]);
        if (act) {
            const float* wb = wbuf[bcur];
            const int kb = T << 3;
#pragma unroll
            for (int r = 0; r < 8; ++r) {
                const int k  = kb + r;
                const int kk = (k >> 1) & 7;
                const float4 h0 = ((const float4*)sH)[k * 8 + (tq0 ^ kk)];
                const float4 h1 = ((const float4*)sH)[k * 8 + ((tq0 + 1) ^ kk)];
                const float4 w0 = *(const float4*)(wb + r * 512 + wcol);
                const float4 w1 = *(const float4*)(wb + r * 512 + 256 + wcol);
#define FMA2(i, s) a0[i].x += (s)*w0.x; a0[i].y += (s)*w0.y;                    \
                   a0[i].z += (s)*w0.z; a0[i].w += (s)*w0.w;                    \
                   a1[i].x += (s)*w1.x; a1[i].y += (s)*w1.y;                    \
                   a1[i].z += (s)*w1.z; a1[i].w += (s)*w1.w;
                FMA2(0, h0.x) FMA2(1, h0.y) FMA2(2, h0.z) FMA2(3, h0.w)
                FMA2(4, h1.x) FMA2(5, h1.y) FMA2(6, h1.z) FMA2(7, h1.w)
#undef FMA2
            }
        }
        if (T < 63) {
            // counted wait: everything older than tile T+2's 4 loads is done
            if (T + 2 < 64) { asm volatile("s_waitcnt vmcnt(4)" ::: "memory"); }
            else            { asm volatile("s_waitcnt vmcnt(0)" ::: "memory"); }
            __builtin_amdgcn_s_barrier();
            asm volatile("" ::: "memory");
            __builtin_amdgcn_sched_barrier(0);
        }
        bcur = bcur + 1; if (bcur == 3) bcur = 0;
    }
#undef STAGE_TILE

    const float* b2 = (mod == 0) ? b2_0 : (mod == 1) ? b2_1 : (mod == 2) ? b2_2 : b2_3;
    const float* te = (mod == 0) ? te_0 : (mod == 1) ? te_1 : (mod == 2) ? te_2 : te_3;
    const int colA = z * 512 + wcol;
    const int colB = colA + 256;
    const float4 bA = *(const float4*)(b2 + cat * EMB + colA);
    const float4 bB = *(const float4*)(b2 + cat * EMB + colB);
    const float4 tA = *(const float4*)(te + colA);
    const float4 tB = *(const float4*)(te + colB);
#pragma unroll
    for (int i = 0; i < 8; ++i) {
        const int t = hbase + i;
        if (t >= nThis) break;
        float* op = out + (size_t)(sTok[t] * 4 + mod) * EMB;
        *(float4*)(op + colA) = make_float4(a0[i].x + bA.x + tA.x,
                                            a0[i].y + bA.y + tA.y,
                                            a0[i].z + bA.z + tA.z,
                                            a0[i].w + bA.w + tA.w);
        *(float4*)(op + colB) = make_float4(a1[i].x + bB.x + tB.x,
                                            a1[i].y + bB.y + tB.y,
                                            a1[i].z + bB.z + tB.z,
                                            a1[i].w + bB.w + tB.w);
    }
}

extern "C" void kernel_launch(void* const* d_in, const int* in_sizes, int n_in,
                              void* d_out, int out_size, void* d_ws, size_t ws_size,
                              hipStream_t stream) {
    const float* state = (const float*)d_in[0];
    const int*   ids   = (const int*)d_in[1];
    const float *W1[4], *b1[4], *W2[4], *b2[4], *te[4];
    for (int m = 0; m < 4; ++m) {
        W1[m] = (const float*)d_in[2 + 5 * m + 0];
        b1[m] = (const float*)d_in[2 + 5 * m + 1];
        W2[m] = (const float*)d_in[2 + 5 * m + 2];
        b2[m] = (const float*)d_in[2 + 5 * m + 3];
        te[m] = (const float*)d_in[2 + 5 * m + 4];
    }
    char* ws = (char*)d_ws;
    int*   cnt     = (int*)ws;
    int*   nW      = (int*)(ws + 128);
    int*   work    = (int*)(ws + 256);
    int*   toklist = (int*)(ws + 1024);
    float* out     = (float*)d_out;

    bucket_kernel<<<1, 512, 0, stream>>>(ids, cnt, nW, work, toklist);
    fused_kernel<<<dim3(MAXW, 4, 2), 256, 0, stream>>>(
        state, cnt, toklist, nW, work,
        W1[0], W1[1], W1[2], W1[3],
        b1[0], b1[1], b1[2], b1[3],
        W2[0], W2[1], W2[2], W2[3],
        b2[0], b2[1], b2[2], b2[3],
        te[0], te[1], te[2], te[3], out);
}